// Round 1
// baseline (257.687 us; speedup 1.0000x reference)
//
#include <hip/hip_runtime.h>

// ICFM: out[s] = sum_{t: seg_ids[t]==s} ( intr_W[intr_idxs[t]] / intr_divs[t]
//                                         * dot(vecs[f0[t]], vecs[f1[t]]) + intr_b[0] )
// T = 1048576, NUM_SEGMENTS = 16384, VEC = 64 floats (256 B/row), table 128 MB.
//
// Mapping: 16 lanes per interaction; lane j loads float4 #j of each row
// (fully coalesced 256 B per row), dot4, then 4-step shfl_xor reduction
// within the 16-lane group. seg_ids sorted -> per-block LDS segment
// accumulator (atomic LDS), flushed with one global atomic per nonzero bin.

#define BLOCK 256
#define CHUNK 512   // interactions per block
#define SMAX  512   // LDS accumulator bins (chunk spans ~8-16 segments typ.)

__global__ __launch_bounds__(BLOCK) void icfm_kernel(
    const int*   __restrict__ intr_idxs,
    const float* __restrict__ intr_divs,
    const int2*  __restrict__ feat_idxs,   // [T] pairs
    const int*   __restrict__ seg_ids,     // sorted
    const float4* __restrict__ vecs,       // [N_FEATS][16] float4
    const float* __restrict__ intr_W,
    const float* __restrict__ intr_b,
    float*       __restrict__ out,
    int n, int num_segments)
{
    __shared__ float acc[SMAX];
    for (int i = threadIdx.x; i < SMAX; i += BLOCK) acc[i] = 0.0f;
    __syncthreads();

    const int chunk_start = blockIdx.x * CHUNK;
    const int first_t = chunk_start < n ? chunk_start : (n - 1);
    const int seg0 = seg_ids[first_t];
    const float b = intr_b[0];

    const int lane16 = threadIdx.x & 15;
    const int group  = threadIdx.x >> 4;   // 16 groups per block

    for (int i = 0; i < CHUNK; i += 16) {
        int t = chunk_start + i + group;
        if (t < n) {
            int2 f = feat_idxs[t];
            float4 a = vecs[(size_t)f.x * 16 + lane16];
            float4 c = vecs[(size_t)f.y * 16 + lane16];
            float d = a.x * c.x + a.y * c.y + a.z * c.z + a.w * c.w;
            // reduce across the 16-lane group (stays inside the wave)
            d += __shfl_xor(d, 1);
            d += __shfl_xor(d, 2);
            d += __shfl_xor(d, 4);
            d += __shfl_xor(d, 8);
            if (lane16 == 0) {
                float w   = intr_W[intr_idxs[t]] / intr_divs[t];
                float val = w * d + b;
                int   s   = seg_ids[t];
                int local = s - seg0;
                if ((unsigned)local < (unsigned)SMAX)
                    atomicAdd(&acc[local], val);       // LDS atomic (hot path)
                else
                    atomicAdd(&out[s], val);           // pathological span fallback
            }
        }
    }
    __syncthreads();

    for (int i = threadIdx.x; i < SMAX; i += BLOCK) {
        float v = acc[i];
        int s = seg0 + i;
        if (v != 0.0f && s < num_segments)
            atomicAdd(&out[s], v);
    }
}

extern "C" void kernel_launch(void* const* d_in, const int* in_sizes, int n_in,
                              void* d_out, int out_size, void* d_ws, size_t ws_size,
                              hipStream_t stream) {
    const int*    intr_idxs = (const int*)   d_in[0];
    const float*  intr_divs = (const float*) d_in[1];
    const int2*   feat_idxs = (const int2*)  d_in[2];
    const int*    seg_ids   = (const int*)   d_in[3];
    const float4* vecs      = (const float4*)d_in[4];
    const float*  intr_W    = (const float*) d_in[5];
    const float*  intr_b    = (const float*) d_in[6];
    float* out = (float*)d_out;

    const int n = in_sizes[0];             // T
    const int num_segments = out_size;     // 16384

    // d_out is re-poisoned to 0xAA before every timed launch
    hipMemsetAsync(d_out, 0, (size_t)out_size * sizeof(float), stream);

    const int grid = (n + CHUNK - 1) / CHUNK;
    icfm_kernel<<<grid, BLOCK, 0, stream>>>(intr_idxs, intr_divs, feat_idxs,
                                            seg_ids, vecs, intr_W, intr_b,
                                            out, n, num_segments);
}

// Round 2
// 248.985 us; speedup vs baseline: 1.0350x; 1.0350x over previous
//
#include <hip/hip_runtime.h>

// ICFM: out[s] = sum_{t: seg_ids[t]==s} ( intr_W[intr_idxs[t]] / intr_divs[t]
//                                         * dot(vecs[f0[t]], vecs[f1[t]]) + intr_b[0] )
// T = 1048576, NUM_SEGMENTS = 16384, VEC = 64 floats (256 B/row), table 128 MB.
//
// R1: latency-bound (VALUBusy 21%, VGPR=16 -> only 2 loads in flight).
// Unroll x4 with explicit load/compute phases -> 8 gathers in flight per wave.
// Metadata loads broadcast across the 16-lane group (1 request each) so they
// issue in the load phase instead of a lane0-predicated tail.

#define BLOCK 256
#define CHUNK 512   // interactions per block
#define SMAX  512   // LDS accumulator bins
#define U     4     // unroll: interactions per group per iteration

__global__ __launch_bounds__(BLOCK) void icfm_kernel(
    const int*   __restrict__ intr_idxs,
    const float* __restrict__ intr_divs,
    const int2*  __restrict__ feat_idxs,   // [T] pairs
    const int*   __restrict__ seg_ids,     // sorted
    const float4* __restrict__ vecs,       // [N_FEATS][16] float4
    const float* __restrict__ intr_W,
    const float* __restrict__ intr_b,
    float*       __restrict__ out,
    int n, int num_segments)
{
    __shared__ float acc[SMAX];
    for (int i = threadIdx.x; i < SMAX; i += BLOCK) acc[i] = 0.0f;
    __syncthreads();

    const int chunk_start = blockIdx.x * CHUNK;
    const int first_t = chunk_start < n ? chunk_start : (n - 1);
    const int seg0 = seg_ids[first_t];
    const float b = intr_b[0];

    const int lane16 = threadIdx.x & 15;
    const int group  = threadIdx.x >> 4;   // 16 groups per block

    for (int i = 0; i < CHUNK; i += 16 * U) {
        const int tb = chunk_start + i + group;

        // ---- load phase: issue all gathers before any consumption ----
        float4 a[U], c[U];
        float  w[U], dv[U];
        int    sg[U];
        bool   ok[U];
        #pragma unroll
        for (int u = 0; u < U; ++u) {
            int t = tb + 16 * u;
            ok[u] = (t < n);
            int tc = ok[u] ? t : first_t;               // safe clamp
            int2 f = feat_idxs[tc];
            a[u]  = vecs[(size_t)f.x * 16 + lane16];
            c[u]  = vecs[(size_t)f.y * 16 + lane16];
            w[u]  = intr_W[intr_idxs[tc]];              // broadcast within group
            dv[u] = intr_divs[tc];
            sg[u] = seg_ids[tc];
        }

        // ---- compute phase ----
        #pragma unroll
        for (int u = 0; u < U; ++u) {
            float d = a[u].x * c[u].x + a[u].y * c[u].y
                    + a[u].z * c[u].z + a[u].w * c[u].w;
            d += __shfl_xor(d, 1);
            d += __shfl_xor(d, 2);
            d += __shfl_xor(d, 4);
            d += __shfl_xor(d, 8);
            if (lane16 == 0 && ok[u]) {
                float val = w[u] / dv[u] * d + b;
                int local = sg[u] - seg0;
                if ((unsigned)local < (unsigned)SMAX)
                    atomicAdd(&acc[local], val);       // LDS atomic (hot path)
                else
                    atomicAdd(&out[sg[u]], val);       // pathological span fallback
            }
        }
    }
    __syncthreads();

    for (int i = threadIdx.x; i < SMAX; i += BLOCK) {
        float v = acc[i];
        int s = seg0 + i;
        if (v != 0.0f && s < num_segments)
            atomicAdd(&out[s], v);
    }
}

extern "C" void kernel_launch(void* const* d_in, const int* in_sizes, int n_in,
                              void* d_out, int out_size, void* d_ws, size_t ws_size,
                              hipStream_t stream) {
    const int*    intr_idxs = (const int*)   d_in[0];
    const float*  intr_divs = (const float*) d_in[1];
    const int2*   feat_idxs = (const int2*)  d_in[2];
    const int*    seg_ids   = (const int*)   d_in[3];
    const float4* vecs      = (const float4*)d_in[4];
    const float*  intr_W    = (const float*) d_in[5];
    const float*  intr_b    = (const float*) d_in[6];
    float* out = (float*)d_out;

    const int n = in_sizes[0];             // T
    const int num_segments = out_size;     // 16384

    // d_out is re-poisoned to 0xAA before every timed launch
    hipMemsetAsync(d_out, 0, (size_t)out_size * sizeof(float), stream);

    const int grid = (n + CHUNK - 1) / CHUNK;
    icfm_kernel<<<grid, BLOCK, 0, stream>>>(intr_idxs, intr_divs, feat_idxs,
                                            seg_ids, vecs, intr_W, intr_b,
                                            out, n, num_segments);
}